// Round 1
// baseline (115.852 us; speedup 1.0000x reference)
//
#include <hip/hip_runtime.h>
#include <math.h>

// L = 64 (hidden dim == wavefront size), P = 3 hard-coded.
#define LDIM 64
#define WAVES 4

// Precompute:
//   B[o,l] = b1[l] + sum_p pos_obs[o,p] * (W1[3+p,l] - W1[6+p,l])
//   V[o,l] = bv[l] + sum_k h_obs[o,k] * Wv[k,l]
__global__ __launch_bounds__(256) void gano_pre(
    const float* __restrict__ h_obs, const float* __restrict__ pos_obs,
    const float* __restrict__ W1, const float* __restrict__ b1,
    const float* __restrict__ Wv, const float* __restrict__ bv,
    float* __restrict__ B, float* __restrict__ V, int No)
{
    int gid = blockIdx.x * blockDim.x + threadIdx.x;
    if (gid >= No * LDIM) return;
    int o = gid >> 6;
    int l = gid & 63;

    float bb = b1[l];
    #pragma unroll
    for (int p = 0; p < 3; ++p) {
        float w = W1[(3 + p) * LDIM + l] - W1[(6 + p) * LDIM + l];
        bb = fmaf(pos_obs[o * 3 + p], w, bb);
    }
    B[gid] = bb;

    float vv = bv[l];
    #pragma unroll 8
    for (int k = 0; k < LDIM; ++k) {
        vv = fmaf(h_obs[o * LDIM + k], Wv[k * LDIM + l], vv);
    }
    V[gid] = vv;
}

// One block (4 waves) per query. Lane = hidden dim. Online masked softmax
// + weighted accumulation of V. Waves split the obs range; merge via LDS.
__global__ __launch_bounds__(256) void gano_main(
    const float* __restrict__ pos_obs, const float* __restrict__ pos_query,
    const float* __restrict__ W1, const float* __restrict__ W2,
    const float* __restrict__ B, const float* __restrict__ V,
    const int* __restrict__ obs_mask, const int* __restrict__ obs_batch,
    const int* __restrict__ query_batch, float* __restrict__ out,
    int No)
{
    const int q    = blockIdx.x;
    const int tid  = threadIdx.x;
    const int lane = tid & 63;
    const int wid  = tid >> 6;

    // Batch range for this query (obs_batch is sorted): two lower_bounds.
    const int b = query_batch[q];
    int lo = 0, hi = No;
    while (lo < hi) { int mid = (lo + hi) >> 1; if (obs_batch[mid] < b) lo = mid + 1; else hi = mid; }
    const int start = lo;
    hi = No;
    while (lo < hi) { int mid = (lo + hi) >> 1; if (obs_batch[mid] < b + 1) lo = mid + 1; else hi = mid; }
    const int end = lo;

    const float pqx = pos_query[q * 3 + 0];
    const float pqy = pos_query[q * 3 + 1];
    const float pqz = pos_query[q * 3 + 2];

    // a_l = sum_p pq_p * (W1[p,l] + W1[6+p,l])   (query-side hidden pre-act)
    float a = 0.0f;
    a = fmaf(pqx, W1[0 * LDIM + lane] + W1[6 * LDIM + lane], a);
    a = fmaf(pqy, W1[1 * LDIM + lane] + W1[7 * LDIM + lane], a);
    a = fmaf(pqz, W1[2 * LDIM + lane] + W1[8 * LDIM + lane], a);
    const float w2 = W2[lane];

    float m = -INFINITY;   // running max (uniform across wave)
    float denom = 0.0f;    // running sum of e (uniform)
    float acc = 0.0f;      // per-lane: sum_o e_o * V[o, lane]

    for (int o = start + wid; o < end; o += WAVES) {
        if (obs_mask[o] == 0) continue;
        const float dx = pqx - pos_obs[o * 3 + 0];
        const float dy = pqy - pos_obs[o * 3 + 1];
        const float dz = pqz - pos_obs[o * 3 + 2];
        const float d2 = fmaf(dz, dz, fmaf(dy, dy, dx * dx));
        if (sqrtf(d2) > 1.0f) continue;

        float h = a + B[o * LDIM + lane];
        h = fmaxf(h, 0.0f);
        float p = h * w2;
        // full 64-lane reduce -> logit broadcast to all lanes
        #pragma unroll
        for (int msk = 1; msk < 64; msk <<= 1) p += __shfl_xor(p, msk, 64);
        const float logit = p;

        const float vv = V[o * LDIM + lane];
        const float nm = fmaxf(m, logit);
        const float s  = expf(m - nm);     // 0 on first hit (m = -inf)
        const float e  = expf(logit - nm);
        denom = fmaf(denom, s, e);
        acc   = fmaf(acc, s, e * vv);
        m = nm;
    }

    __shared__ float s_m[WAVES];
    __shared__ float s_d[WAVES];
    __shared__ float s_acc[WAVES][LDIM];
    if (lane == 0) { s_m[wid] = m; s_d[wid] = denom; }
    s_acc[wid][lane] = acc;
    __syncthreads();

    if (wid == 0) {
        float M = s_m[0];
        #pragma unroll
        for (int w = 1; w < WAVES; ++w) M = fmaxf(M, s_m[w]);
        float D = 0.0f, A = 0.0f;
        #pragma unroll
        for (int w = 0; w < WAVES; ++w) {
            const float sc = (s_m[w] == -INFINITY) ? 0.0f : expf(s_m[w] - M);
            D = fmaf(s_d[w], sc, D);
            A = fmaf(s_acc[w][lane], sc, A);
        }
        // fully-masked row: all sc = 0 -> A = 0, D = 0 -> out = 0 (matches ref)
        out[q * LDIM + lane] = A / fmaxf(D, 1e-30f);
    }
}

extern "C" void kernel_launch(void* const* d_in, const int* in_sizes, int n_in,
                              void* d_out, int out_size, void* d_ws, size_t ws_size,
                              hipStream_t stream) {
    const float* h_obs     = (const float*)d_in[0];
    const float* pos_obs   = (const float*)d_in[1];
    const float* pos_query = (const float*)d_in[2];
    const float* W1        = (const float*)d_in[3];
    const float* b1        = (const float*)d_in[4];
    const float* W2        = (const float*)d_in[5];
    // d_in[6] = b2: constant shift, cancels in softmax -> unused
    const float* Wv        = (const float*)d_in[7];
    const float* bv        = (const float*)d_in[8];
    const int* obs_mask    = (const int*)d_in[9];
    const int* obs_batch   = (const int*)d_in[10];
    const int* query_batch = (const int*)d_in[11];

    const int No = in_sizes[1] / 3;
    const int Nq = in_sizes[2] / 3;

    float* B = (float*)d_ws;           // No*64 floats
    float* V = B + (size_t)No * LDIM;  // No*64 floats

    const int pre_threads = 256;
    const int pre_blocks  = (No * LDIM + pre_threads - 1) / pre_threads;
    gano_pre<<<pre_blocks, pre_threads, 0, stream>>>(h_obs, pos_obs, W1, b1, Wv, bv, B, V, No);

    gano_main<<<Nq, 256, 0, stream>>>(pos_obs, pos_query, W1, W2, B, V,
                                      obs_mask, obs_batch, query_batch,
                                      (float*)d_out, No);
}

// Round 2
// 40.968 us; speedup vs baseline: 2.8278x; 2.8278x over previous
//
#include <hip/hip_runtime.h>
#include <math.h>

#define LDIM 64
#define WAVES 4
#define LOG2E 1.4426950408889634f

static __device__ __forceinline__ float fast_exp2(float x) {
#if __has_builtin(__builtin_amdgcn_exp2f)
    return __builtin_amdgcn_exp2f(x);
#else
    return exp2f(x);
#endif
}

// Precompute (all guarded to NoA = No rounded up to 64):
//   Bblk[c][l][oin] = b1[l] + sum_p pos_obs[o,p]*(W1[3+p,l]-W1[6+p,l]),  o = c*64+oin
//   V[o][l]         = bv[l] + sum_k h_obs[o,k]*Wv[k,l]
//   P4[o]           = (x, y, z, mask ? 1 : 0)
__global__ __launch_bounds__(256) void gano_pre(
    const float* __restrict__ h_obs, const float* __restrict__ pos_obs,
    const float* __restrict__ W1, const float* __restrict__ b1,
    const float* __restrict__ Wv, const float* __restrict__ bv,
    const int* __restrict__ obs_mask,
    float* __restrict__ Bblk, float* __restrict__ V, float4* __restrict__ P4,
    int No, int NoA)
{
    int gid = blockIdx.x * blockDim.x + threadIdx.x;
    if (gid >= NoA * LDIM) return;

    // --- Bblk (write-linear: gid = c*4096 + l*64 + oin) ---
    {
        int c   = gid >> 12;
        int rem = gid & 4095;
        int l   = rem >> 6;
        int oin = rem & 63;
        int o   = (c << 6) + oin;
        float bb = 0.0f;
        if (o < No) {
            bb = b1[l];
            #pragma unroll
            for (int p = 0; p < 3; ++p)
                bb = fmaf(pos_obs[o * 3 + p], W1[(3 + p) * LDIM + l] - W1[(6 + p) * LDIM + l], bb);
        }
        Bblk[gid] = bb;
    }
    // --- V (row-major: gid = o*64 + l) ---
    {
        int o = gid >> 6;
        int l = gid & 63;
        float vv = 0.0f;
        if (o < No) {
            vv = bv[l];
            #pragma unroll 8
            for (int k = 0; k < LDIM; ++k)
                vv = fmaf(h_obs[o * LDIM + k], Wv[k * LDIM + l], vv);
        }
        V[gid] = vv;
    }
    // --- P4 ---
    if (gid < NoA) {
        float4 pp = make_float4(0.f, 0.f, 0.f, 0.f);
        if (gid < No)
            pp = make_float4(pos_obs[gid * 3 + 0], pos_obs[gid * 3 + 1],
                             pos_obs[gid * 3 + 2], obs_mask[gid] ? 1.0f : 0.0f);
        P4[gid] = pp;
    }
}

// One block (4 waves) per query. Chunks of 64 obs aligned to absolute
// 64-boundaries; waves stride chunks. Logit phase: lane = obs. PV phase:
// lane = hidden dim, e broadcast from wave-private LDS. Log2-domain softmax.
__global__ __launch_bounds__(256) void gano_main(
    const float* __restrict__ pos_query, const float* __restrict__ W1,
    const float* __restrict__ W2,
    const float* __restrict__ Bblk, const float* __restrict__ V,
    const float4* __restrict__ P4,
    const int* __restrict__ obs_batch, const int* __restrict__ query_batch,
    float* __restrict__ out, int No)
{
    const int q    = blockIdx.x;
    const int tid  = threadIdx.x;
    const int lane = tid & 63;
    const int wid  = tid >> 6;

    __shared__ float2 aw[LDIM];            // (a_l, w2_l * log2e)
    __shared__ float  e_lds[WAVES][LDIM];  // wave-private e buffers
    __shared__ float  s_m[WAVES], s_d[WAVES];
    __shared__ float  s_acc[WAVES][LDIM];

    // Batch range [start,end) for this query (obs_batch sorted).
    const int b = query_batch[q];
    int lo = 0, hi = No;
    while (lo < hi) { int mid = (lo + hi) >> 1; if (obs_batch[mid] < b) lo = mid + 1; else hi = mid; }
    const int start = lo;
    hi = No;
    while (lo < hi) { int mid = (lo + hi) >> 1; if (obs_batch[mid] < b + 1) lo = mid + 1; else hi = mid; }
    const int end = lo;

    const float pqx = pos_query[q * 3 + 0];
    const float pqy = pos_query[q * 3 + 1];
    const float pqz = pos_query[q * 3 + 2];

    if (tid < LDIM) {
        const int l = tid;
        float a = 0.0f;
        a = fmaf(pqx, W1[0 * LDIM + l] + W1[6 * LDIM + l], a);
        a = fmaf(pqy, W1[1 * LDIM + l] + W1[7 * LDIM + l], a);
        a = fmaf(pqz, W1[2 * LDIM + l] + W1[8 * LDIM + l], a);
        aw[l] = make_float2(a, W2[l] * LOG2E);
    }
    __syncthreads();

    float m    = -INFINITY;  // running max (log2 domain, wave-uniform)
    float dden = 0.0f;       // per-lane denom partial (obs-slot layout)
    float acc0 = 0.0f;       // per-lane acc partials (hidden-dim layout)
    float acc1 = 0.0f;

    if (end > start) {
        const int c0 = start >> 6;
        const int c1 = (end - 1) >> 6;
        for (int c = c0 + wid; c <= c1; c += WAVES) {
            const int o = (c << 6) + lane;
            const float4 p = P4[o];

            // --- logit phase: lane = obs ---
            const float* Bc = Bblk + ((size_t)c << 12) + lane;
            float lg0 = 0.0f, lg1 = 0.0f;
            #pragma unroll
            for (int l = 0; l < LDIM; l += 2) {
                const float2 aw0 = aw[l];
                const float2 aw1 = aw[l + 1];
                const float t0 = fmaxf(aw0.x + Bc[l * LDIM], 0.0f);
                const float t1 = fmaxf(aw1.x + Bc[(l + 1) * LDIM], 0.0f);
                lg0 = fmaf(t0, aw0.y, lg0);
                lg1 = fmaf(t1, aw1.y, lg1);
            }
            float lg = lg0 + lg1;  // logit * log2e

            const float dx = pqx - p.x, dy = pqy - p.y, dz = pqz - p.z;
            const float d2 = fmaf(dz, dz, fmaf(dy, dy, dx * dx));
            const bool valid = (o >= start) & (o < end) & (p.w != 0.0f) & (d2 <= 1.0f);
            lg = valid ? lg : -INFINITY;

            // chunk max (amortized over 64 obs)
            float cm = lg;
            #pragma unroll
            for (int msk = 32; msk; msk >>= 1) cm = fmaxf(cm, __shfl_xor(cm, msk, 64));

            if (cm > -INFINITY) {  // wave-uniform
                const float nm = fmaxf(m, cm);
                const float sc = fast_exp2(m - nm);  // 0 on first chunk
                m = nm;
                const float e = fast_exp2(lg - nm);  // 0 for invalid lanes
                dden = fmaf(dden, sc, e);
                acc0 *= sc;
                acc1 *= sc;
                e_lds[wid][lane] = e;

                // --- PV phase: lane = hidden dim ---
                const float* Vc = V + ((size_t)c << 12) + lane;
                #pragma unroll
                for (int o2 = 0; o2 < LDIM; o2 += 2) {
                    const float e0 = e_lds[wid][o2];
                    const float e1 = e_lds[wid][o2 + 1];
                    acc0 = fmaf(e0, Vc[o2 * LDIM], acc0);
                    acc1 = fmaf(e1, Vc[(o2 + 1) * LDIM], acc1);
                }
            }
        }
    }

    // per-wave: reduce denom partials over lanes
    float denom = dden;
    #pragma unroll
    for (int msk = 32; msk; msk >>= 1) denom += __shfl_xor(denom, msk, 64);

    if (lane == 0) { s_m[wid] = m; s_d[wid] = denom; }
    s_acc[wid][lane] = acc0 + acc1;
    __syncthreads();

    if (wid == 0) {
        float M = s_m[0];
        #pragma unroll
        for (int w = 1; w < WAVES; ++w) M = fmaxf(M, s_m[w]);
        float D = 0.0f, A = 0.0f;
        #pragma unroll
        for (int w = 0; w < WAVES; ++w) {
            const float sc = (s_m[w] == -INFINITY) ? 0.0f : fast_exp2(s_m[w] - M);
            D = fmaf(s_d[w], sc, D);
            A = fmaf(s_acc[w][lane], sc, A);
        }
        out[q * LDIM + lane] = A / fmaxf(D, 1e-30f);
    }
}

extern "C" void kernel_launch(void* const* d_in, const int* in_sizes, int n_in,
                              void* d_out, int out_size, void* d_ws, size_t ws_size,
                              hipStream_t stream) {
    const float* h_obs     = (const float*)d_in[0];
    const float* pos_obs   = (const float*)d_in[1];
    const float* pos_query = (const float*)d_in[2];
    const float* W1        = (const float*)d_in[3];
    const float* b1        = (const float*)d_in[4];
    const float* W2        = (const float*)d_in[5];
    // d_in[6] = b2: constant shift, cancels in softmax -> unused
    const float* Wv        = (const float*)d_in[7];
    const float* bv        = (const float*)d_in[8];
    const int* obs_mask    = (const int*)d_in[9];
    const int* obs_batch   = (const int*)d_in[10];
    const int* query_batch = (const int*)d_in[11];

    const int No  = in_sizes[1] / 3;
    const int Nq  = in_sizes[2] / 3;
    const int NoA = (No + 63) & ~63;

    float*  Bblk = (float*)d_ws;                     // NoA*64 floats
    float*  V    = Bblk + (size_t)NoA * LDIM;        // NoA*64 floats
    float4* P4   = (float4*)(V + (size_t)NoA * LDIM); // NoA float4s

    const int pre_threads = 256;
    const int pre_blocks  = (NoA * LDIM + pre_threads - 1) / pre_threads;
    gano_pre<<<pre_blocks, pre_threads, 0, stream>>>(h_obs, pos_obs, W1, b1, Wv, bv,
                                                     obs_mask, Bblk, V, P4, No, NoA);

    gano_main<<<Nq, 256, 0, stream>>>(pos_query, W1, W2, Bblk, V, P4,
                                      obs_batch, query_batch, (float*)d_out, No);
}